// Round 1
// baseline (186.706 us; speedup 1.0000x reference)
//
#include <hip/hip_runtime.h>
#include <hip/hip_bf16.h>
#include <math.h>

// Problem geometry (fixed by reference):
//   x: [B=16, C=256, 128, 128] fp32 ; H = 16 ; spatial N = 16384
#define BATCH 16
#define CH    256
#define HID   16
#define SPAT  16384   // 128*128

// ---------------------------------------------------------------------------
// Kernel 1: per-(b,c) spatial mean & biased std. One block per (b,c).
// ---------------------------------------------------------------------------
__global__ __launch_bounds__(256) void stats_kernel(const float* __restrict__ x,
                                                    float* __restrict__ mean_g,
                                                    float* __restrict__ std_g)
{
    const long long base = (long long)blockIdx.x * SPAT;
    const float4* x4 = reinterpret_cast<const float4*>(x + base);

    float s = 0.f, s2 = 0.f;
    #pragma unroll
    for (int i = 0; i < 16; ++i) {
        float4 v = x4[threadIdx.x + i * 256];
        s  += v.x + v.y + v.z + v.w;
        s2 += v.x * v.x + v.y * v.y + v.z * v.z + v.w * v.w;
    }

    // wave64 butterfly reduce
    #pragma unroll
    for (int off = 32; off > 0; off >>= 1) {
        s  += __shfl_xor(s,  off);
        s2 += __shfl_xor(s2, off);
    }

    __shared__ float ws[4], ws2[4];
    const int wave = threadIdx.x >> 6;
    const int lane = threadIdx.x & 63;
    if (lane == 0) { ws[wave] = s; ws2[wave] = s2; }
    __syncthreads();

    if (threadIdx.x == 0) {
        const float ts  = ws[0]  + ws[1]  + ws[2]  + ws[3];
        const float ts2 = ws2[0] + ws2[1] + ws2[2] + ws2[3];
        const float m   = ts * (1.f / SPAT);
        const float var = ts2 * (1.f / SPAT) - m * m;
        mean_g[blockIdx.x] = m;
        std_g[blockIdx.x]  = sqrtf(fmaxf(var, 0.f));
    }
}

// ---------------------------------------------------------------------------
// Kernel 2: SE chain on the [16, 256] descriptors. One block per batch row.
//   se(d, w1, b1, w2, b2) = (relu(d @ w1^T + b1)) @ w2^T + b2
//   fused = relu(concat(se_std, se_mean) @ bw^T + bb)
//   mask  = sigmoid(se(fused, fw1, fb1, fw2, fb2))
// ---------------------------------------------------------------------------
__global__ __launch_bounds__(256) void se_chain_kernel(
    const float* __restrict__ mean_g, const float* __restrict__ std_g,
    const float* __restrict__ sw1, const float* __restrict__ sb1,
    const float* __restrict__ sw2, const float* __restrict__ sb2,
    const float* __restrict__ mw1, const float* __restrict__ mb1,
    const float* __restrict__ mw2, const float* __restrict__ mb2,
    const float* __restrict__ bw,  const float* __restrict__ bb,
    const float* __restrict__ fw1, const float* __restrict__ fb1,
    const float* __restrict__ fw2, const float* __restrict__ fb2,
    float* __restrict__ mask_g)
{
    const int b   = blockIdx.x;
    const int tid = threadIdx.x;   // 256 threads

    __shared__ float s_desc[2 * CH];   // [std | mean]
    __shared__ float s_h[HID];
    __shared__ float s_fused[2 * CH];  // [se_std | se_mean], reused for nothing else
    __shared__ float s_g[CH];          // bottleneck output

    s_desc[tid]      = std_g [b * CH + tid];
    s_desc[CH + tid] = mean_g[b * CH + tid];
    __syncthreads();

    // --- layer1 of an SE block: s_h[hh] = relu(sum_c desc[c]*w1[hh,c] + b1[hh])
    // 16 threads per output hh; partial sums reduced with width-16 shuffles.
    auto se_l1 = [&](const float* desc, const float* __restrict__ w1,
                     const float* __restrict__ b1) {
        const int hh = tid >> 4;      // 0..15
        const int j  = tid & 15;      // 0..15
        float acc = 0.f;
        #pragma unroll
        for (int k = 0; k < 16; ++k) {
            const int c = j * 16 + k;
            acc += desc[c] * w1[hh * CH + c];
        }
        #pragma unroll
        for (int off = 1; off < 16; off <<= 1)
            acc += __shfl_xor(acc, off, 16);
        if (j == 0) s_h[hh] = fmaxf(acc + b1[hh], 0.f);
    };

    // --- layer2 of an SE block: out[c] = sum_h s_h[h]*w2[c,h] + b2[c]
    auto se_l2 = [&](const float* __restrict__ w2, const float* __restrict__ b2,
                     float* outbuf) {
        float acc = b2[tid];
        const float4* w4 = reinterpret_cast<const float4*>(w2 + tid * HID);
        #pragma unroll
        for (int q = 0; q < 4; ++q) {
            const float4 w = w4[q];
            acc += s_h[q * 4 + 0] * w.x + s_h[q * 4 + 1] * w.y
                 + s_h[q * 4 + 2] * w.z + s_h[q * 4 + 3] * w.w;
        }
        outbuf[tid] = acc;
    };

    // SE(std) -> fused[0:256]
    se_l1(s_desc, sw1, sb1);
    __syncthreads();
    se_l2(sw2, sb2, s_fused);
    __syncthreads();

    // SE(mean) -> fused[256:512]
    se_l1(s_desc + CH, mw1, mb1);
    __syncthreads();
    se_l2(mw2, mb2, s_fused + CH);
    __syncthreads();

    // bottleneck: g[c] = relu(sum_d fused[d] * bw[c,d] + bb[c])
    {
        float acc = bb[tid];
        const float4* wrow = reinterpret_cast<const float4*>(bw + tid * (2 * CH));
        const float4* f4   = reinterpret_cast<const float4*>(s_fused);
        #pragma unroll 8
        for (int q = 0; q < (2 * CH) / 4; ++q) {
            const float4 w = wrow[q];
            const float4 f = f4[q];
            acc += f.x * w.x + f.y * w.y + f.z * w.z + f.w * w.w;
        }
        s_g[tid] = fmaxf(acc, 0.f);
    }
    __syncthreads();

    // final SE + sigmoid -> mask
    se_l1(s_g, fw1, fb1);
    __syncthreads();
    {
        float acc = fb2[tid];
        const float4* w4 = reinterpret_cast<const float4*>(fw2 + tid * HID);
        #pragma unroll
        for (int q = 0; q < 4; ++q) {
            const float4 w = w4[q];
            acc += s_h[q * 4 + 0] * w.x + s_h[q * 4 + 1] * w.y
                 + s_h[q * 4 + 2] * w.z + s_h[q * 4 + 3] * w.w;
        }
        mask_g[b * CH + tid] = 1.f / (1.f + expf(-acc));
    }
}

// ---------------------------------------------------------------------------
// Kernel 3: out = x * mask[b,c]. One block per (b,c), coalesced float4.
// ---------------------------------------------------------------------------
__global__ __launch_bounds__(256) void scale_kernel(const float* __restrict__ x,
                                                    const float* __restrict__ mask,
                                                    float* __restrict__ out)
{
    const float m = mask[blockIdx.x];
    const long long base = (long long)blockIdx.x * SPAT;
    const float4* x4 = reinterpret_cast<const float4*>(x + base);
    float4*       o4 = reinterpret_cast<float4*>(out + base);
    #pragma unroll
    for (int i = 0; i < 16; ++i) {
        float4 v = x4[threadIdx.x + i * 256];
        v.x *= m; v.y *= m; v.z *= m; v.w *= m;
        o4[threadIdx.x + i * 256] = v;
    }
}

// ---------------------------------------------------------------------------
extern "C" void kernel_launch(void* const* d_in, const int* in_sizes, int n_in,
                              void* d_out, int out_size, void* d_ws, size_t ws_size,
                              hipStream_t stream)
{
    const float* x   = (const float*)d_in[0];
    const float* sw1 = (const float*)d_in[1];
    const float* sb1 = (const float*)d_in[2];
    const float* sw2 = (const float*)d_in[3];
    const float* sb2 = (const float*)d_in[4];
    const float* mw1 = (const float*)d_in[5];
    const float* mb1 = (const float*)d_in[6];
    const float* mw2 = (const float*)d_in[7];
    const float* mb2 = (const float*)d_in[8];
    const float* bw  = (const float*)d_in[9];
    const float* bb  = (const float*)d_in[10];
    const float* fw1 = (const float*)d_in[11];
    const float* fb1 = (const float*)d_in[12];
    const float* fw2 = (const float*)d_in[13];
    const float* fb2 = (const float*)d_in[14];

    float* out = (float*)d_out;

    float* ws     = (float*)d_ws;
    float* mean_g = ws;                 // 4096 floats
    float* std_g  = ws + BATCH * CH;    // 4096 floats
    float* mask_g = ws + 2 * BATCH * CH;// 4096 floats

    const int nbc = BATCH * CH;  // 4096 blocks

    stats_kernel<<<nbc, 256, 0, stream>>>(x, mean_g, std_g);
    se_chain_kernel<<<BATCH, 256, 0, stream>>>(mean_g, std_g,
                                               sw1, sb1, sw2, sb2,
                                               mw1, mb1, mw2, mb2,
                                               bw, bb,
                                               fw1, fb1, fw2, fb2,
                                               mask_g);
    scale_kernel<<<nbc, 256, 0, stream>>>(x, mask_g, out);
}

// Round 3
// 148.412 us; speedup vs baseline: 1.2580x; 1.2580x over previous
//
#include <hip/hip_runtime.h>
#include <hip/hip_bf16.h>
#include <math.h>

// Problem geometry (fixed by reference):
//   x: [B=16, C=256, 128, 128] fp32 ; H = 16 ; spatial N = 16384
#define BATCH 16
#define CH    256
#define HID   16
#define SPAT  16384   // 128*128

// clang-native 16B vector — accepted by __builtin_nontemporal_store
typedef float vfloat4 __attribute__((ext_vector_type(4)));

// ---------------------------------------------------------------------------
// Kernel 1: per-(b,c) spatial mean & biased std. One block per (b,c).
// Reads x FORWARD -> after completion the L3 (256 MiB) holds the tail of x.
// ---------------------------------------------------------------------------
__global__ __launch_bounds__(256) void stats_kernel(const float* __restrict__ x,
                                                    float* __restrict__ mean_g,
                                                    float* __restrict__ std_g)
{
    const long long base = (long long)blockIdx.x * SPAT;
    const vfloat4* x4 = reinterpret_cast<const vfloat4*>(x + base);

    float s = 0.f, s2 = 0.f;
    #pragma unroll
    for (int i = 0; i < 16; ++i) {
        vfloat4 v = x4[threadIdx.x + i * 256];
        s  += v.x + v.y + v.z + v.w;
        s2 += v.x * v.x + v.y * v.y + v.z * v.z + v.w * v.w;
    }

    // wave64 butterfly reduce
    #pragma unroll
    for (int off = 32; off > 0; off >>= 1) {
        s  += __shfl_xor(s,  off);
        s2 += __shfl_xor(s2, off);
    }

    __shared__ float ws[4], ws2[4];
    const int wave = threadIdx.x >> 6;
    const int lane = threadIdx.x & 63;
    if (lane == 0) { ws[wave] = s; ws2[wave] = s2; }
    __syncthreads();

    if (threadIdx.x == 0) {
        const float ts  = ws[0]  + ws[1]  + ws[2]  + ws[3];
        const float ts2 = ws2[0] + ws2[1] + ws2[2] + ws2[3];
        const float m   = ts * (1.f / SPAT);
        const float var = ts2 * (1.f / SPAT) - m * m;
        mean_g[blockIdx.x] = m;
        std_g[blockIdx.x]  = sqrtf(fmaxf(var, 0.f));
    }
}

// ---------------------------------------------------------------------------
// Kernel 2: SE chain on the [16, 256] descriptors. One block per batch row.
// ---------------------------------------------------------------------------
__global__ __launch_bounds__(256) void se_chain_kernel(
    const float* __restrict__ mean_g, const float* __restrict__ std_g,
    const float* __restrict__ sw1, const float* __restrict__ sb1,
    const float* __restrict__ sw2, const float* __restrict__ sb2,
    const float* __restrict__ mw1, const float* __restrict__ mb1,
    const float* __restrict__ mw2, const float* __restrict__ mb2,
    const float* __restrict__ bw,  const float* __restrict__ bb,
    const float* __restrict__ fw1, const float* __restrict__ fb1,
    const float* __restrict__ fw2, const float* __restrict__ fb2,
    float* __restrict__ mask_g)
{
    const int b   = blockIdx.x;
    const int tid = threadIdx.x;   // 256 threads

    __shared__ float s_desc[2 * CH];   // [std | mean]
    __shared__ float s_h[HID];
    __shared__ float s_fused[2 * CH];  // [se_std | se_mean]
    __shared__ float s_g[CH];          // bottleneck output

    s_desc[tid]      = std_g [b * CH + tid];
    s_desc[CH + tid] = mean_g[b * CH + tid];
    __syncthreads();

    // layer1: s_h[hh] = relu(sum_c desc[c]*w1[hh,c] + b1[hh]); 16 lanes per hh
    auto se_l1 = [&](const float* desc, const float* __restrict__ w1,
                     const float* __restrict__ b1) {
        const int hh = tid >> 4;
        const int j  = tid & 15;
        float acc = 0.f;
        #pragma unroll
        for (int k = 0; k < 16; ++k) {
            const int c = j * 16 + k;
            acc += desc[c] * w1[hh * CH + c];
        }
        #pragma unroll
        for (int off = 1; off < 16; off <<= 1)
            acc += __shfl_xor(acc, off, 16);
        if (j == 0) s_h[hh] = fmaxf(acc + b1[hh], 0.f);
    };

    // layer2: out[c] = sum_h s_h[h]*w2[c,h] + b2[c]
    auto se_l2 = [&](const float* __restrict__ w2, const float* __restrict__ b2,
                     float* outbuf) {
        float acc = b2[tid];
        const vfloat4* w4 = reinterpret_cast<const vfloat4*>(w2 + tid * HID);
        #pragma unroll
        for (int q = 0; q < 4; ++q) {
            const vfloat4 w = w4[q];
            acc += s_h[q * 4 + 0] * w.x + s_h[q * 4 + 1] * w.y
                 + s_h[q * 4 + 2] * w.z + s_h[q * 4 + 3] * w.w;
        }
        outbuf[tid] = acc;
    };

    se_l1(s_desc, sw1, sb1);
    __syncthreads();
    se_l2(sw2, sb2, s_fused);
    __syncthreads();

    se_l1(s_desc + CH, mw1, mb1);
    __syncthreads();
    se_l2(mw2, mb2, s_fused + CH);
    __syncthreads();

    // bottleneck: g[c] = relu(sum_d fused[d] * bw[c,d] + bb[c])
    {
        float acc = bb[tid];
        const vfloat4* wrow = reinterpret_cast<const vfloat4*>(bw + tid * (2 * CH));
        const vfloat4* f4   = reinterpret_cast<const vfloat4*>(s_fused);
        #pragma unroll 8
        for (int q = 0; q < (2 * CH) / 4; ++q) {
            const vfloat4 w = wrow[q];
            const vfloat4 f = f4[q];
            acc += f.x * w.x + f.y * w.y + f.z * w.z + f.w * w.w;
        }
        s_g[tid] = fmaxf(acc, 0.f);
    }
    __syncthreads();

    se_l1(s_g, fw1, fb1);
    __syncthreads();
    {
        float acc = fb2[tid];
        const vfloat4* w4 = reinterpret_cast<const vfloat4*>(fw2 + tid * HID);
        #pragma unroll
        for (int q = 0; q < 4; ++q) {
            const vfloat4 w = w4[q];
            acc += s_h[q * 4 + 0] * w.x + s_h[q * 4 + 1] * w.y
                 + s_h[q * 4 + 2] * w.z + s_h[q * 4 + 3] * w.w;
        }
        mask_g[b * CH + tid] = 1.f / (1.f + expf(-acc));
    }
}

// ---------------------------------------------------------------------------
// Kernel 3: out = x * mask[b,c].
// REVERSE plane order: the L3 holds the tail of x after stats_kernel, so we
// start reading where the cache is hot. Non-temporal stores for `out` so the
// write stream does not evict the x lines we are about to read.
// ---------------------------------------------------------------------------
__global__ __launch_bounds__(256) void scale_kernel(const float* __restrict__ x,
                                                    const float* __restrict__ mask,
                                                    float* __restrict__ out)
{
    const int plane = (BATCH * CH - 1) - blockIdx.x;   // reverse order
    const float m = mask[plane];
    const long long base = (long long)plane * SPAT;
    const vfloat4* x4 = reinterpret_cast<const vfloat4*>(x + base);
    vfloat4*       o4 = reinterpret_cast<vfloat4*>(out + base);
    #pragma unroll
    for (int i = 0; i < 16; ++i) {
        vfloat4 v = x4[threadIdx.x + i * 256];
        v *= m;
        __builtin_nontemporal_store(v, &o4[threadIdx.x + i * 256]);
    }
}

// ---------------------------------------------------------------------------
extern "C" void kernel_launch(void* const* d_in, const int* in_sizes, int n_in,
                              void* d_out, int out_size, void* d_ws, size_t ws_size,
                              hipStream_t stream)
{
    const float* x   = (const float*)d_in[0];
    const float* sw1 = (const float*)d_in[1];
    const float* sb1 = (const float*)d_in[2];
    const float* sw2 = (const float*)d_in[3];
    const float* sb2 = (const float*)d_in[4];
    const float* mw1 = (const float*)d_in[5];
    const float* mb1 = (const float*)d_in[6];
    const float* mw2 = (const float*)d_in[7];
    const float* mb2 = (const float*)d_in[8];
    const float* bw  = (const float*)d_in[9];
    const float* bb  = (const float*)d_in[10];
    const float* fw1 = (const float*)d_in[11];
    const float* fb1 = (const float*)d_in[12];
    const float* fw2 = (const float*)d_in[13];
    const float* fb2 = (const float*)d_in[14];

    float* out = (float*)d_out;

    float* ws     = (float*)d_ws;
    float* mean_g = ws;                  // 4096 floats
    float* std_g  = ws + BATCH * CH;     // 4096 floats
    float* mask_g = ws + 2 * BATCH * CH; // 4096 floats

    const int nbc = BATCH * CH;  // 4096 blocks

    stats_kernel<<<nbc, 256, 0, stream>>>(x, mean_g, std_g);
    se_chain_kernel<<<BATCH, 256, 0, stream>>>(mean_g, std_g,
                                               sw1, sb1, sw2, sb2,
                                               mw1, mb1, mw2, mb2,
                                               bw, bb,
                                               fw1, fb1, fw2, fb2,
                                               mask_g);
    scale_kernel<<<nbc, 256, 0, stream>>>(x, mask_g, out);
}